// Round 5
// baseline (486.533 us; speedup 1.0000x reference)
//
#include <hip/hip_runtime.h>

typedef unsigned short u16;
typedef unsigned int u32;
typedef __bf16 bf16_8 __attribute__((ext_vector_type(8)));
typedef short s16x8 __attribute__((ext_vector_type(8)));
typedef short s16x4 __attribute__((ext_vector_type(4)));
typedef float f32x4 __attribute__((ext_vector_type(4)));
typedef u32 u32x2 __attribute__((ext_vector_type(2)));

#define NQ 2048
#define BSZ 2
#define EDIM 1024
#define NH 16
#define HDIM 64
#define MROWS (NQ * BSZ)   // 4096
#define F3 (3 * EDIM)      // 3072

// 16x16x16 bf16 MFMA — device pass only (host pass lacks amdgcn builtins).
#if defined(__HIP_DEVICE_COMPILE__)
#if __has_builtin(__builtin_amdgcn_mfma_f32_16x16x16bf16_1k)
#define MFMA16(A, B, C) __builtin_amdgcn_mfma_f32_16x16x16bf16_1k((A), (B), (C), 0, 0, 0)
#elif __has_builtin(__builtin_amdgcn_mfma_f32_16x16x16_bf16_1k)
#define MFMA16(A, B, C) __builtin_amdgcn_mfma_f32_16x16x16_bf16_1k((A), (B), (C), 0, 0, 0)
#else
#error "no 16x16x16 bf16 mfma builtin on this target"
#endif
#else
#define MFMA16(A, B, C) (C)
#endif

__device__ __forceinline__ float bf2f(u16 u) {
  u32 x = ((u32)u) << 16;
  return __builtin_bit_cast(float, x);
}
__device__ __forceinline__ u16 f2bf(float f) {
  u32 x = __builtin_bit_cast(u32, f);
  x += 0x7fff + ((x >> 16) & 1);  // RNE
  return (u16)(x >> 16);
}
__device__ __forceinline__ u32 cvtpk_bf16(float lo, float hi) {
  u32 r;
  asm("v_cvt_pk_bf16_f32 %0, %1, %2" : "=v"(r) : "v"(lo), "v"(hi));
  return r;
}
__device__ __forceinline__ void gload16(const u16* g, u16* l) {
  __builtin_amdgcn_global_load_lds(
      (const __attribute__((address_space(1))) void*)g,
      (__attribute__((address_space(3))) void*)l, 16, 0, 0);
}

// ---------------------------------------------------------------------------
__global__ __launch_bounds__(256) void cvt_f32_bf16(
    const float* __restrict__ in, u16* __restrict__ out, int n) {
  int i = (blockIdx.x * 256 + threadIdx.x) * 4;
  const int stride = gridDim.x * 256 * 4;
  for (; i < n; i += stride) {
    f32x4 v = *(const f32x4*)&in[i];
    s16x4 o;
    o[0] = (short)f2bf(v[0]);
    o[1] = (short)f2bf(v[1]);
    o[2] = (short)f2bf(v[2]);
    o[3] = (short)f2bf(v[3]);
    *(s16x4*)&out[i] = o;
  }
}

// ---------------------------------------------------------------------------
// GEMM C = A*B^T + bias, global_load_lds staging (m97 pattern, line-verified).
// ---------------------------------------------------------------------------
template <int MODE>
__global__ __launch_bounds__(256) void gemm_bt(
    const u16* __restrict__ A, const u16* __restrict__ B,
    const float* __restrict__ bias, int K,
    u16* __restrict__ out0, u16* __restrict__ out1, u16* __restrict__ out2,
    float* __restrict__ outf) {
  constexpr int BM = 128, BN = 128, BK = 32;
  __shared__ u16 As[BM * BK];
  __shared__ u16 Bs[BN * BK];
  const int tid = threadIdx.x;
  const int wid = tid >> 6, lane = tid & 63;
  const int wm = wid >> 1, wn = wid & 1;
  const int row0 = blockIdx.y * BM, col0 = blockIdx.x * BN;
  const int g = lane >> 4, l15 = lane & 15;
  const int lr = tid >> 2, lc8 = (tid & 3) * 8;

  f32x4 acc[4][4];
#pragma unroll
  for (int m = 0; m < 4; ++m)
#pragma unroll
    for (int n = 0; n < 4; ++n) acc[m][n] = f32x4{0.f, 0.f, 0.f, 0.f};

  for (int kb = 0; kb < K; kb += BK) {
    __syncthreads();
#pragma unroll
    for (int c = 0; c < 2; ++c) {
      gload16(&A[(size_t)(row0 + c * 64 + lr) * K + kb + lc8],
              &As[c * 2048 + wid * 512]);
      gload16(&B[(size_t)(col0 + c * 64 + lr) * K + kb + lc8],
              &Bs[c * 2048 + wid * 512]);
    }
    __syncthreads();
    bf16_8 af[4], bf[4];
#pragma unroll
    for (int m = 0; m < 4; ++m)
      af[m] = __builtin_bit_cast(
          bf16_8, *(const s16x8*)&As[(wm * 64 + m * 16 + l15) * BK + g * 8]);
#pragma unroll
    for (int n = 0; n < 4; ++n)
      bf[n] = __builtin_bit_cast(
          bf16_8, *(const s16x8*)&Bs[(wn * 64 + n * 16 + l15) * BK + g * 8]);
#pragma unroll
    for (int m = 0; m < 4; ++m)
#pragma unroll
      for (int n = 0; n < 4; ++n)
        acc[m][n] = __builtin_amdgcn_mfma_f32_16x16x32_bf16(af[m], bf[n],
                                                            acc[m][n], 0, 0, 0);
  }

  const int orow = row0 + wm * 64;
  const int ocol = col0 + wn * 64;
#pragma unroll
  for (int m = 0; m < 4; ++m) {
#pragma unroll
    for (int n = 0; n < 4; ++n) {
      const int f = ocol + n * 16 + l15;
      const float bv = bias[f];
#pragma unroll
      for (int j = 0; j < 4; ++j) {
        const int r = orow + m * 16 + g * 4 + j;
        const float v = acc[m][n][j] + bv;
        if (MODE == 0) {
          const int part = f >> 10, e = f & 1023;
          const int h = e >> 6, d = e & 63;
          const int nq = r >> 1, b = r & 1;
          const int bh = b * NH + h;
          if (part == 0)
            out0[((size_t)bh * NQ + nq) * HDIM + d] = f2bf(v * 0.125f);
          else if (part == 1)
            out1[((size_t)bh * NQ + nq) * HDIM + d] = f2bf(v);
          else
            out2[((size_t)bh * HDIM + d) * NQ + nq] = f2bf(v);
        } else {
          outf[(size_t)r * EDIM + f] = v;
        }
      }
    }
  }
}

// ---------------------------------------------------------------------------
// SAFE attention — round-2-proven path, 32 q-rows/wave (qb=0,1).
// QK: mfma(A=Q,B=K) -> lane holds S[q=4g+j][key=n*16+l15]; P->LDS (f2bf);
// PV: mfma(A=P,B=V) with verified 16x16x32 frags.
// ---------------------------------------------------------------------------
__global__ __launch_bounds__(256) void attn_safe(
    const u16* __restrict__ Qs, const u16* __restrict__ Ks,
    const u16* __restrict__ Vt, u16* __restrict__ AO) {
  __shared__ u16 Kt[64][72];        // [key][d]
  __shared__ u16 Vs[64][72];        // [d][key]
  __shared__ u16 Pl[4][2][16][72];  // per-wave, per-qb: [q][key]
  const int tid = threadIdx.x;
  const int wid = tid >> 6, lane = tid & 63;
  const int g = lane >> 4, l15 = lane & 15;
  const int bh = blockIdx.y;
  const int qrow = blockIdx.x * 128 + wid * 32;

  bf16_8 qf[2][2];
#pragma unroll
  for (int qb = 0; qb < 2; ++qb)
#pragma unroll
    for (int c = 0; c < 2; ++c)
      qf[qb][c] = __builtin_bit_cast(
          bf16_8, *(const s16x8*)&Qs[((size_t)bh * NQ + qrow + qb * 16 + l15) *
                                         HDIM + c * 32 + g * 8]);

  f32x4 oacc[2][4];
#pragma unroll
  for (int qb = 0; qb < 2; ++qb)
#pragma unroll
    for (int n = 0; n < 4; ++n) oacc[qb][n] = f32x4{0.f, 0.f, 0.f, 0.f};
  float rs[2][4] = {{0.f, 0.f, 0.f, 0.f}, {0.f, 0.f, 0.f, 0.f}};

  for (int kt = 0; kt < NQ; kt += 64) {
    __syncthreads();
#pragma unroll
    for (int c = 0; c < 2; ++c) {
      int id = c * 256 + tid;
      int r = id >> 3, c8 = (id & 7) * 8;
      *(s16x8*)&Kt[r][c8] =
          *(const s16x8*)&Ks[((size_t)bh * NQ + kt + r) * HDIM + c8];
      *(s16x8*)&Vs[r][c8] =
          *(const s16x8*)&Vt[((size_t)bh * HDIM + r) * NQ + kt + c8];
    }
    __syncthreads();

#pragma unroll
    for (int n = 0; n < 4; ++n) {
      bf16_8 kf0 = __builtin_bit_cast(bf16_8, *(const s16x8*)&Kt[n * 16 + l15][g * 8]);
      bf16_8 kf1 = __builtin_bit_cast(bf16_8, *(const s16x8*)&Kt[n * 16 + l15][32 + g * 8]);
#pragma unroll
      for (int qb = 0; qb < 2; ++qb) {
        f32x4 s = f32x4{0.f, 0.f, 0.f, 0.f};
        s = __builtin_amdgcn_mfma_f32_16x16x32_bf16(qf[qb][0], kf0, s, 0, 0, 0);
        s = __builtin_amdgcn_mfma_f32_16x16x32_bf16(qf[qb][1], kf1, s, 0, 0, 0);
#pragma unroll
        for (int j = 0; j < 4; ++j) {
          float p = __expf(s[j]);
          rs[qb][j] += p;
          Pl[wid][qb][g * 4 + j][n * 16 + l15] = f2bf(p);
        }
      }
    }

#pragma unroll
    for (int n = 0; n < 4; ++n) {
      bf16_8 vf0 = __builtin_bit_cast(bf16_8, *(const s16x8*)&Vs[n * 16 + l15][g * 8]);
      bf16_8 vf1 = __builtin_bit_cast(bf16_8, *(const s16x8*)&Vs[n * 16 + l15][32 + g * 8]);
#pragma unroll
      for (int qb = 0; qb < 2; ++qb) {
        bf16_8 pf0 = __builtin_bit_cast(bf16_8, *(const s16x8*)&Pl[wid][qb][l15][g * 8]);
        bf16_8 pf1 = __builtin_bit_cast(bf16_8, *(const s16x8*)&Pl[wid][qb][l15][32 + g * 8]);
        oacc[qb][n] = __builtin_amdgcn_mfma_f32_16x16x32_bf16(pf0, vf0, oacc[qb][n], 0, 0, 0);
        oacc[qb][n] = __builtin_amdgcn_mfma_f32_16x16x32_bf16(pf1, vf1, oacc[qb][n], 0, 0, 0);
      }
    }
  }

  const int b = bh >> 4, h = bh & 15;
#pragma unroll
  for (int qb = 0; qb < 2; ++qb) {
    float inv[4];
#pragma unroll
    for (int j = 0; j < 4; ++j) {
      float t = rs[qb][j];
      t += __shfl_xor(t, 1);
      t += __shfl_xor(t, 2);
      t += __shfl_xor(t, 4);
      t += __shfl_xor(t, 8);
      inv[j] = 1.0f / t;
    }
#pragma unroll
    for (int n = 0; n < 4; ++n)
#pragma unroll
      for (int j = 0; j < 4; ++j) {
        const int q = qrow + qb * 16 + g * 4 + j;
        AO[((size_t)q * BSZ + b) * EDIM + h * 64 + n * 16 + l15] =
            f2bf(oacc[qb][n][j] * inv[j]);
      }
  }
}

// ---------------------------------------------------------------------------
// RISKY attention (round-4 design) — PROBE ONLY, writes scratch AO2.
// ---------------------------------------------------------------------------
__global__ __launch_bounds__(256) void attn_risky(
    const u16* __restrict__ Qs, const u16* __restrict__ Ks,
    const u16* __restrict__ Vt, u16* __restrict__ AO) {
  __shared__ u16 Kt[64][72];
  __shared__ u16 Vs[64][72];
  const int tid = threadIdx.x;
  const int wid = tid >> 6, lane = tid & 63;
  const int g = lane >> 4, l15 = lane & 15;
  const int bh = blockIdx.y;
  const int qrow = blockIdx.x * 128 + wid * 32;

  bf16_8 qf[2][2];
#pragma unroll
  for (int qb = 0; qb < 2; ++qb)
#pragma unroll
    for (int c = 0; c < 2; ++c)
      qf[qb][c] = __builtin_bit_cast(
          bf16_8, *(const s16x8*)&Qs[((size_t)bh * NQ + qrow + qb * 16 + l15) *
                                         HDIM + c * 32 + g * 8]);

  f32x4 oT[2][4];
#pragma unroll
  for (int qb = 0; qb < 2; ++qb)
#pragma unroll
    for (int nd = 0; nd < 4; ++nd) oT[qb][nd] = f32x4{0.f, 0.f, 0.f, 0.f};
  float rs[2] = {0.f, 0.f};

  for (int kt = 0; kt < NQ; kt += 64) {
    __syncthreads();
#pragma unroll
    for (int c = 0; c < 2; ++c) {
      int id = c * 256 + tid;
      int r = id >> 3, c8 = (id & 7) * 8;
      *(s16x8*)&Kt[r][c8] =
          *(const s16x8*)&Ks[((size_t)bh * NQ + kt + r) * HDIM + c8];
      *(s16x8*)&Vs[r][c8] =
          *(const s16x8*)&Vt[((size_t)bh * HDIM + r) * NQ + kt + c8];
    }
    __syncthreads();

    u32 pw[2][4][2];
#pragma unroll
    for (int n = 0; n < 4; ++n) {
      bf16_8 kf0 = __builtin_bit_cast(bf16_8, *(const s16x8*)&Kt[n * 16 + l15][g * 8]);
      bf16_8 kf1 = __builtin_bit_cast(bf16_8, *(const s16x8*)&Kt[n * 16 + l15][32 + g * 8]);
#pragma unroll
      for (int qb = 0; qb < 2; ++qb) {
        f32x4 s = f32x4{0.f, 0.f, 0.f, 0.f};
        s = __builtin_amdgcn_mfma_f32_16x16x32_bf16(kf0, qf[qb][0], s, 0, 0, 0);
        s = __builtin_amdgcn_mfma_f32_16x16x32_bf16(kf1, qf[qb][1], s, 0, 0, 0);
        float p0 = __expf(s[0]), p1 = __expf(s[1]);
        float p2 = __expf(s[2]), p3 = __expf(s[3]);
        rs[qb] += (p0 + p1) + (p2 + p3);
        pw[qb][n][0] = cvtpk_bf16(p0, p1);
        pw[qb][n][1] = cvtpk_bf16(p2, p3);
      }
    }

#pragma unroll
    for (int nd = 0; nd < 4; ++nd) {
#pragma unroll
      for (int n = 0; n < 4; ++n) {
        s16x4 vf = *(const s16x4*)&Vs[nd * 16 + l15][n * 16 + g * 4];
#pragma unroll
        for (int qb = 0; qb < 2; ++qb) {
          s16x4 pf = __builtin_bit_cast(s16x4, u32x2{pw[qb][n][0], pw[qb][n][1]});
          oT[qb][nd] = MFMA16(vf, pf, oT[qb][nd]);
        }
      }
    }
  }

  float inv[2];
#pragma unroll
  for (int qb = 0; qb < 2; ++qb) {
    float t = rs[qb];
    t += __shfl_xor(t, 16);
    t += __shfl_xor(t, 32);
    inv[qb] = 1.0f / t;
  }
  const int b = bh >> 4, h = bh & 15;
#pragma unroll
  for (int qb = 0; qb < 2; ++qb) {
    const int q = qrow + qb * 16 + l15;
#pragma unroll
    for (int nd = 0; nd < 4; ++nd) {
      s16x4 o;
#pragma unroll
      for (int j = 0; j < 4; ++j) o[j] = (short)f2bf(oT[qb][nd][j] * inv[qb]);
      *(s16x4*)&AO[((size_t)q * BSZ + b) * EDIM + h * 64 + nd * 16 + g * 4] = o;
    }
  }
}

// ---------------------------------------------------------------------------
// Probe: per-block max|a-b|; spin if above threshold -> dispatch dur = verdict.
// ---------------------------------------------------------------------------
__global__ __launch_bounds__(256) void diff_probe(
    const u16* __restrict__ a, const u16* __restrict__ b,
    float* __restrict__ sink) {
  __shared__ float red[4];
  float m = 0.f;
  for (size_t i = (size_t)blockIdx.x * 256 + threadIdx.x;
       i < (size_t)MROWS * EDIM; i += (size_t)gridDim.x * 256)
    m = fmaxf(m, fabsf(bf2f(a[i]) - bf2f(b[i])));
#pragma unroll
  for (int o = 1; o < 64; o <<= 1) m = fmaxf(m, __shfl_xor(m, o));
  if ((threadIdx.x & 63) == 0) red[threadIdx.x >> 6] = m;
  __syncthreads();
  if (threadIdx.x == 0) {
    float bm = fmaxf(fmaxf(red[0], red[1]), fmaxf(red[2], red[3]));
    float acc = bm;
    if (bm > 2e-3f)  // benign reorder diffs <= ~2.5e-4; bug-level >= 1e-2
      for (int i = 0; i < 50000; ++i) acc = fmaf(acc, 1.0000001f, 1e-9f);
    sink[blockIdx.x] = acc;
  }
}

// ---------------------------------------------------------------------------
extern "C" void kernel_launch(void* const* d_in, const int* in_sizes, int n_in,
                              void* d_out, int out_size, void* d_ws,
                              size_t ws_size, hipStream_t stream) {
  const float* seq = (const float*)d_in[0];
  const float* w_qkv = (const float*)d_in[1];
  const float* b_qkv = (const float*)d_in[2];
  const float* w_out = (const float*)d_in[3];
  const float* b_out = (const float*)d_in[4];
  float* out = (float*)d_out;

  const size_t per = (size_t)BSZ * NH * NQ * HDIM;  // 4,194,304
  u16* Qs = (u16*)d_ws;
  u16* Ks = Qs + per;
  u16* Vt = Ks + per;
  u16* AO = Vt + per;
  u16* seqb = AO + (size_t)MROWS * EDIM;
  u16* wqkvb = seqb + (size_t)MROWS * EDIM;
  u16* woutb = wqkvb + (size_t)F3 * EDIM;
  u16* AO2 = woutb + (size_t)EDIM * EDIM;
  float* sink = (float*)(AO2 + (size_t)MROWS * EDIM);
  // bytes needed incl. probe: 58,720,256 + 1KB sink
  const bool probe = ws_size >= 58722304ULL;

  cvt_f32_bf16<<<1024, 256, 0, stream>>>(seq, seqb, MROWS * EDIM);
  cvt_f32_bf16<<<1024, 256, 0, stream>>>(w_qkv, wqkvb, F3 * EDIM);
  cvt_f32_bf16<<<512, 256, 0, stream>>>(w_out, woutb, EDIM * EDIM);

  gemm_bt<0><<<dim3(F3 / 128, MROWS / 128), 256, 0, stream>>>(
      seqb, wqkvb, b_qkv, EDIM, Qs, Ks, Vt, nullptr);
  attn_safe<<<dim3(NQ / 128, BSZ * NH), 256, 0, stream>>>(Qs, Ks, Vt, AO);
  if (probe) {
    attn_risky<<<dim3(NQ / 128, BSZ * NH), 256, 0, stream>>>(Qs, Ks, Vt, AO2);
    diff_probe<<<256, 256, 0, stream>>>(AO, AO2, sink);
  }
  gemm_bt<1><<<dim3(EDIM / 128, MROWS / 128), 256, 0, stream>>>(
      AO, woutb, b_out, EDIM, nullptr, nullptr, nullptr, out);
}

// Round 6
// 237.790 us; speedup vs baseline: 2.0461x; 2.0461x over previous
//
#include <hip/hip_runtime.h>

typedef unsigned short u16;
typedef unsigned int u32;
typedef __bf16 bf16_8 __attribute__((ext_vector_type(8)));
typedef short s16x8 __attribute__((ext_vector_type(8)));
typedef short s16x4 __attribute__((ext_vector_type(4)));
typedef float f32x4 __attribute__((ext_vector_type(4)));

#define NQ 2048
#define BSZ 2
#define EDIM 1024
#define NH 16
#define HDIM 64
#define MROWS (NQ * BSZ)   // 4096
#define F3 (3 * EDIM)      // 3072

__device__ __forceinline__ u16 f2bf(float f) {
  u32 x = __builtin_bit_cast(u32, f);
  x += 0x7fff + ((x >> 16) & 1);  // RNE
  return (u16)(x >> 16);
}
__device__ __forceinline__ void gload16(const u16* g, u16* l) {
  __builtin_amdgcn_global_load_lds(
      (const __attribute__((address_space(1))) void*)g,
      (__attribute__((address_space(3))) void*)l, 16, 0, 0);
}

// ---------------------------------------------------------------------------
__global__ __launch_bounds__(256) void cvt_f32_bf16(
    const float* __restrict__ in, u16* __restrict__ out, int n) {
  int i = (blockIdx.x * 256 + threadIdx.x) * 4;
  const int stride = gridDim.x * 256 * 4;
  for (; i < n; i += stride) {
    f32x4 v = *(const f32x4*)&in[i];
    s16x4 o;
    o[0] = (short)f2bf(v[0]);
    o[1] = (short)f2bf(v[1]);
    o[2] = (short)f2bf(v[2]);
    o[3] = (short)f2bf(v[3]);
    *(s16x4*)&out[i] = o;
  }
}

// ---------------------------------------------------------------------------
// GEMM C = A*B^T + bias, global_load_lds staging (m97 pattern; verified R5).
// ---------------------------------------------------------------------------
template <int MODE>
__global__ __launch_bounds__(256) void gemm_bt(
    const u16* __restrict__ A, const u16* __restrict__ B,
    const float* __restrict__ bias, int K,
    u16* __restrict__ out0, u16* __restrict__ out1, u16* __restrict__ out2,
    float* __restrict__ outf) {
  constexpr int BM = 128, BN = 128, BK = 32;
  __shared__ u16 As[BM * BK];
  __shared__ u16 Bs[BN * BK];
  const int tid = threadIdx.x;
  const int wid = tid >> 6, lane = tid & 63;
  const int wm = wid >> 1, wn = wid & 1;
  const int row0 = blockIdx.y * BM, col0 = blockIdx.x * BN;
  const int g = lane >> 4, l15 = lane & 15;
  const int lr = tid >> 2, lc8 = (tid & 3) * 8;

  f32x4 acc[4][4];
#pragma unroll
  for (int m = 0; m < 4; ++m)
#pragma unroll
    for (int n = 0; n < 4; ++n) acc[m][n] = f32x4{0.f, 0.f, 0.f, 0.f};

  for (int kb = 0; kb < K; kb += BK) {
    __syncthreads();
#pragma unroll
    for (int c = 0; c < 2; ++c) {
      gload16(&A[(size_t)(row0 + c * 64 + lr) * K + kb + lc8],
              &As[c * 2048 + wid * 512]);
      gload16(&B[(size_t)(col0 + c * 64 + lr) * K + kb + lc8],
              &Bs[c * 2048 + wid * 512]);
    }
    __syncthreads();
    bf16_8 af[4], bf[4];
#pragma unroll
    for (int m = 0; m < 4; ++m)
      af[m] = __builtin_bit_cast(
          bf16_8, *(const s16x8*)&As[(wm * 64 + m * 16 + l15) * BK + g * 8]);
#pragma unroll
    for (int n = 0; n < 4; ++n)
      bf[n] = __builtin_bit_cast(
          bf16_8, *(const s16x8*)&Bs[(wn * 64 + n * 16 + l15) * BK + g * 8]);
#pragma unroll
    for (int m = 0; m < 4; ++m)
#pragma unroll
      for (int n = 0; n < 4; ++n)
        acc[m][n] = __builtin_amdgcn_mfma_f32_16x16x32_bf16(af[m], bf[n],
                                                            acc[m][n], 0, 0, 0);
  }

  const int orow = row0 + wm * 64;
  const int ocol = col0 + wn * 64;
#pragma unroll
  for (int m = 0; m < 4; ++m) {
#pragma unroll
    for (int n = 0; n < 4; ++n) {
      const int f = ocol + n * 16 + l15;
      const float bv = bias[f];
#pragma unroll
      for (int j = 0; j < 4; ++j) {
        const int r = orow + m * 16 + g * 4 + j;
        const float v = acc[m][n][j] + bv;
        if (MODE == 0) {
          const int part = f >> 10, e = f & 1023;
          const int h = e >> 6, d = e & 63;
          const int nq = r >> 1, b = r & 1;
          const int bh = b * NH + h;
          if (part == 0)
            out0[((size_t)bh * NQ + nq) * HDIM + d] = f2bf(v * 0.125f);
          else if (part == 1)
            out1[((size_t)bh * NQ + nq) * HDIM + d] = f2bf(v);
          else
            out2[((size_t)bh * HDIM + d) * NQ + nq] = f2bf(v);
        } else {
          outf[(size_t)r * EDIM + f] = v;
        }
      }
    }
  }
}

// ---------------------------------------------------------------------------
// Attention (R5-verified math, bit-exact). 32 q-rows/wave, 128/block.
// P tile swizzled: [16 q][64 key] u16 per (wave,qb); 16B key-chunk index is
// XORed with (q>>1)&7 -> write side exactly 2 lanes/bank (free), reads stay
// ds_read_b128-legal (granule-preserving XOR).
// ---------------------------------------------------------------------------
__global__ __launch_bounds__(256) void attn_fwd(
    const u16* __restrict__ Qs, const u16* __restrict__ Ks,
    const u16* __restrict__ Vt, u16* __restrict__ AO) {
  __shared__ u16 Kt[64][72];       // [key][d], +pad
  __shared__ u16 Vs[64][72];       // [d][key], +pad
  __shared__ u16 Pl[4][2][16 * 64];  // [wave][qb][swizzled q*64+key]
  const int tid = threadIdx.x;
  const int wid = tid >> 6, lane = tid & 63;
  const int g = lane >> 4, l15 = lane & 15;
  const int bh = blockIdx.y;
  const int qrow = blockIdx.x * 128 + wid * 32;
  const int rxor = (l15 >> 1) & 7;  // read-side chunk XOR (q = l15)

  bf16_8 qf[2][2];
#pragma unroll
  for (int qb = 0; qb < 2; ++qb)
#pragma unroll
    for (int c = 0; c < 2; ++c)
      qf[qb][c] = __builtin_bit_cast(
          bf16_8, *(const s16x8*)&Qs[((size_t)bh * NQ + qrow + qb * 16 + l15) *
                                         HDIM + c * 32 + g * 8]);

  f32x4 oacc[2][4];
#pragma unroll
  for (int qb = 0; qb < 2; ++qb)
#pragma unroll
    for (int n = 0; n < 4; ++n) oacc[qb][n] = f32x4{0.f, 0.f, 0.f, 0.f};
  float rs[2][4] = {{0.f, 0.f, 0.f, 0.f}, {0.f, 0.f, 0.f, 0.f}};

  for (int kt = 0; kt < NQ; kt += 64) {
    __syncthreads();
#pragma unroll
    for (int c = 0; c < 2; ++c) {
      int id = c * 256 + tid;
      int r = id >> 3, c8 = (id & 7) * 8;
      *(s16x8*)&Kt[r][c8] =
          *(const s16x8*)&Ks[((size_t)bh * NQ + kt + r) * HDIM + c8];
      *(s16x8*)&Vs[r][c8] =
          *(const s16x8*)&Vt[((size_t)bh * HDIM + r) * NQ + kt + c8];
    }
    __syncthreads();

    // S = QK^T: lane holds S[q=4g+j][key=16n+l15]; P -> swizzled LDS
#pragma unroll
    for (int n = 0; n < 4; ++n) {
      bf16_8 kf0 = __builtin_bit_cast(bf16_8, *(const s16x8*)&Kt[n * 16 + l15][g * 8]);
      bf16_8 kf1 = __builtin_bit_cast(bf16_8, *(const s16x8*)&Kt[n * 16 + l15][32 + g * 8]);
      const int chunk = 2 * n + (l15 >> 3), wsub = l15 & 7;
#pragma unroll
      for (int qb = 0; qb < 2; ++qb) {
        f32x4 s = f32x4{0.f, 0.f, 0.f, 0.f};
        s = __builtin_amdgcn_mfma_f32_16x16x32_bf16(qf[qb][0], kf0, s, 0, 0, 0);
        s = __builtin_amdgcn_mfma_f32_16x16x32_bf16(qf[qb][1], kf1, s, 0, 0, 0);
#pragma unroll
        for (int j = 0; j < 4; ++j) {
          float p = __expf(s[j]);
          rs[qb][j] += p;
          const int q = g * 4 + j;
          Pl[wid][qb][q * 64 + ((chunk ^ ((q >> 1) & 7)) << 3) + wsub] = f2bf(p);
        }
      }
    }

    // O += P*V: A-frag rows q=l15 (chunks g / g+4), B-frag = V^T rows d
#pragma unroll
    for (int n = 0; n < 4; ++n) {
      bf16_8 vf0 = __builtin_bit_cast(bf16_8, *(const s16x8*)&Vs[n * 16 + l15][g * 8]);
      bf16_8 vf1 = __builtin_bit_cast(bf16_8, *(const s16x8*)&Vs[n * 16 + l15][32 + g * 8]);
#pragma unroll
      for (int qb = 0; qb < 2; ++qb) {
        bf16_8 pf0 = __builtin_bit_cast(
            bf16_8, *(const s16x8*)&Pl[wid][qb][l15 * 64 + ((g ^ rxor) << 3)]);
        bf16_8 pf1 = __builtin_bit_cast(
            bf16_8, *(const s16x8*)&Pl[wid][qb][l15 * 64 + (((g + 4) ^ rxor) << 3)]);
        oacc[qb][n] = __builtin_amdgcn_mfma_f32_16x16x32_bf16(pf0, vf0, oacc[qb][n], 0, 0, 0);
        oacc[qb][n] = __builtin_amdgcn_mfma_f32_16x16x32_bf16(pf1, vf1, oacc[qb][n], 0, 0, 0);
      }
    }
  }

  const int b = bh >> 4, h = bh & 15;
#pragma unroll
  for (int qb = 0; qb < 2; ++qb) {
    float inv[4];
#pragma unroll
    for (int j = 0; j < 4; ++j) {
      float t = rs[qb][j];
      t += __shfl_xor(t, 1);
      t += __shfl_xor(t, 2);
      t += __shfl_xor(t, 4);
      t += __shfl_xor(t, 8);
      inv[j] = 1.0f / t;
    }
#pragma unroll
    for (int n = 0; n < 4; ++n)
#pragma unroll
      for (int j = 0; j < 4; ++j) {
        const int q = qrow + qb * 16 + g * 4 + j;
        AO[((size_t)q * BSZ + b) * EDIM + h * 64 + n * 16 + l15] =
            f2bf(oacc[qb][n][j] * inv[j]);
      }
  }
}

// ---------------------------------------------------------------------------
extern "C" void kernel_launch(void* const* d_in, const int* in_sizes, int n_in,
                              void* d_out, int out_size, void* d_ws,
                              size_t ws_size, hipStream_t stream) {
  const float* seq = (const float*)d_in[0];
  const float* w_qkv = (const float*)d_in[1];
  const float* b_qkv = (const float*)d_in[2];
  const float* w_out = (const float*)d_in[3];
  const float* b_out = (const float*)d_in[4];
  float* out = (float*)d_out;

  const size_t per = (size_t)BSZ * NH * NQ * HDIM;  // 4,194,304
  u16* Qs = (u16*)d_ws;
  u16* Ks = Qs + per;
  u16* Vt = Ks + per;
  u16* AO = Vt + per;
  u16* seqb = AO + (size_t)MROWS * EDIM;
  u16* wqkvb = seqb + (size_t)MROWS * EDIM;
  u16* woutb = wqkvb + (size_t)F3 * EDIM;

  cvt_f32_bf16<<<1024, 256, 0, stream>>>(seq, seqb, MROWS * EDIM);
  cvt_f32_bf16<<<1024, 256, 0, stream>>>(w_qkv, wqkvb, F3 * EDIM);
  cvt_f32_bf16<<<512, 256, 0, stream>>>(w_out, woutb, EDIM * EDIM);

  gemm_bt<0><<<dim3(F3 / 128, MROWS / 128), 256, 0, stream>>>(
      seqb, wqkvb, b_qkv, EDIM, Qs, Ks, Vt, nullptr);
  attn_fwd<<<dim3(NQ / 128, BSZ * NH), 256, 0, stream>>>(Qs, Ks, Vt, AO);
  gemm_bt<1><<<dim3(EDIM / 128, MROWS / 128), 256, 0, stream>>>(
      AO, woutb, b_out, EDIM, nullptr, nullptr, nullptr, out);
}

// Round 7
// 235.662 us; speedup vs baseline: 2.0645x; 1.0090x over previous
//
#include <hip/hip_runtime.h>

typedef unsigned short u16;
typedef unsigned int u32;
typedef __bf16 bf16_8 __attribute__((ext_vector_type(8)));
typedef short s16x8 __attribute__((ext_vector_type(8)));
typedef short s16x4 __attribute__((ext_vector_type(4)));
typedef float f32x4 __attribute__((ext_vector_type(4)));

#define NQ 2048
#define BSZ 2
#define EDIM 1024
#define NH 16
#define HDIM 64
#define MROWS (NQ * BSZ)   // 4096
#define F3 (3 * EDIM)      // 3072

__device__ __forceinline__ float bf2f(u16 u) {
  u32 x = ((u32)u) << 16;
  return __builtin_bit_cast(float, x);
}
__device__ __forceinline__ u16 f2bf(float f) {
  u32 x = __builtin_bit_cast(u32, f);
  x += 0x7fff + ((x >> 16) & 1);  // RNE
  return (u16)(x >> 16);
}
__device__ __forceinline__ void gload16(const u16* g, u16* l) {
  __builtin_amdgcn_global_load_lds(
      (const __attribute__((address_space(1))) void*)g,
      (__attribute__((address_space(3))) void*)l, 16, 0, 0);
}

// ---------------------------------------------------------------------------
__global__ __launch_bounds__(256) void cvt_f32_bf16(
    const float* __restrict__ in, u16* __restrict__ out, int n) {
  int i = (blockIdx.x * 256 + threadIdx.x) * 4;
  const int stride = gridDim.x * 256 * 4;
  for (; i < n; i += stride) {
    f32x4 v = *(const f32x4*)&in[i];
    s16x4 o;
    o[0] = (short)f2bf(v[0]);
    o[1] = (short)f2bf(v[1]);
    o[2] = (short)f2bf(v[2]);
    o[3] = (short)f2bf(v[3]);
    *(s16x4*)&out[i] = o;
  }
}

// ---------------------------------------------------------------------------
// QKV GEMM: C = A*B^T + bias, A[4096][1024], B[3072][1024] bf16.
// 256x192 tile, 8 waves (2x4), BK=32, DOUBLE-buffered gload_lds staging,
// ONE barrier per K-iter: STAGE(next) issued before compute(cur) so HBM/L3
// latency hides under the 24 MFMAs. Grid 16x16 = 256 blocks = 1/CU exact.
// ---------------------------------------------------------------------------
__global__ __launch_bounds__(512, 2) void gemm_qkv(
    const u16* __restrict__ A, const u16* __restrict__ B,
    const float* __restrict__ bias,
    u16* __restrict__ out0, u16* __restrict__ out1, u16* __restrict__ out2) {
  constexpr int K = EDIM;
  __shared__ u16 As[2][256 * 32];  // 32 KB
  __shared__ u16 Bs[2][192 * 32];  // 24 KB
  const int tid = threadIdx.x;
  const int wid = tid >> 6, lane = tid & 63;
  const int wr = wid >> 2, wc = wid & 3;          // 2 x 4 waves
  const int row0 = blockIdx.y * 256, col0 = blockIdx.x * 192;
  const int g = lane >> 4, l15 = lane & 15;
  const int lr = tid >> 2, lc8 = (tid & 3) * 8;   // 128 rows x 4 granules

  auto STAGE = [&](int buf, int kb) {
    gload16(&A[(size_t)(row0 + lr) * K + kb + lc8], &As[buf][wid * 512]);
    gload16(&A[(size_t)(row0 + 128 + lr) * K + kb + lc8],
            &As[buf][4096 + wid * 512]);
    gload16(&B[(size_t)(col0 + lr) * K + kb + lc8], &Bs[buf][wid * 512]);
    if (tid < 256)  // rows 128..191 (wave-uniform branch)
      gload16(&B[(size_t)(col0 + 128 + lr) * K + kb + lc8],
              &Bs[buf][4096 + wid * 512]);
  };

  f32x4 acc[8][3];
#pragma unroll
  for (int m = 0; m < 8; ++m)
#pragma unroll
    for (int n = 0; n < 3; ++n) acc[m][n] = f32x4{0.f, 0.f, 0.f, 0.f};

  STAGE(0, 0);
  __syncthreads();
  int cur = 0;
  for (int t = 0; t < 32; ++t) {
    if (t < 31) STAGE(cur ^ 1, (t + 1) * 32);
    bf16_8 af[8], bf[3];
#pragma unroll
    for (int m = 0; m < 8; ++m)
      af[m] = __builtin_bit_cast(
          bf16_8, *(const s16x8*)&As[cur][(wr * 128 + m * 16 + l15) * 32 + g * 8]);
#pragma unroll
    for (int n = 0; n < 3; ++n)
      bf[n] = __builtin_bit_cast(
          bf16_8, *(const s16x8*)&Bs[cur][(wc * 48 + n * 16 + l15) * 32 + g * 8]);
#pragma unroll
    for (int m = 0; m < 8; ++m)
#pragma unroll
      for (int n = 0; n < 3; ++n)
        acc[m][n] = __builtin_amdgcn_mfma_f32_16x16x32_bf16(af[m], bf[n],
                                                            acc[m][n], 0, 0, 0);
    __syncthreads();
    cur ^= 1;
  }

  const int orow = row0 + wr * 128;
  const int ocol = col0 + wc * 48;
#pragma unroll
  for (int m = 0; m < 8; ++m) {
#pragma unroll
    for (int n = 0; n < 3; ++n) {
      const int f = ocol + n * 16 + l15;
      const float bv = bias[f];
#pragma unroll
      for (int j = 0; j < 4; ++j) {
        const int r = orow + m * 16 + g * 4 + j;
        const float v = acc[m][n][j] + bv;
        const int part = f >> 10, e = f & 1023;
        const int h = e >> 6, d = e & 63;
        const int nq = r >> 1, b = r & 1;
        const int bh = b * NH + h;
        if (part == 0)
          out0[((size_t)bh * NQ + nq) * HDIM + d] = f2bf(v * 0.125f);
        else if (part == 1)
          out1[((size_t)bh * NQ + nq) * HDIM + d] = f2bf(v);
        else
          out2[((size_t)bh * HDIM + d) * NQ + nq] = f2bf(v);
      }
    }
  }
}

// ---------------------------------------------------------------------------
// Output GEMM: 128x128 tile, 4 waves, dbuf gload_lds, one barrier/iter.
// ---------------------------------------------------------------------------
__global__ __launch_bounds__(256) void gemm_out(
    const u16* __restrict__ A, const u16* __restrict__ B,
    const float* __restrict__ bias, float* __restrict__ outf) {
  constexpr int K = EDIM;
  __shared__ u16 As[2][128 * 32];
  __shared__ u16 Bs[2][128 * 32];
  const int tid = threadIdx.x;
  const int wid = tid >> 6, lane = tid & 63;
  const int wm = wid >> 1, wn = wid & 1;
  const int row0 = blockIdx.y * 128, col0 = blockIdx.x * 128;
  const int g = lane >> 4, l15 = lane & 15;
  const int lr = tid >> 2, lc8 = (tid & 3) * 8;  // 64 rows x 4 granules

  auto STAGE = [&](int buf, int kb) {
#pragma unroll
    for (int s = 0; s < 2; ++s) {
      gload16(&A[(size_t)(row0 + s * 64 + lr) * K + kb + lc8],
              &As[buf][s * 2048 + wid * 512]);
      gload16(&B[(size_t)(col0 + s * 64 + lr) * K + kb + lc8],
              &Bs[buf][s * 2048 + wid * 512]);
    }
  };

  f32x4 acc[4][4];
#pragma unroll
  for (int m = 0; m < 4; ++m)
#pragma unroll
    for (int n = 0; n < 4; ++n) acc[m][n] = f32x4{0.f, 0.f, 0.f, 0.f};

  STAGE(0, 0);
  __syncthreads();
  int cur = 0;
  for (int t = 0; t < 32; ++t) {
    if (t < 31) STAGE(cur ^ 1, (t + 1) * 32);
    bf16_8 af[4], bf[4];
#pragma unroll
    for (int m = 0; m < 4; ++m)
      af[m] = __builtin_bit_cast(
          bf16_8, *(const s16x8*)&As[cur][(wm * 64 + m * 16 + l15) * 32 + g * 8]);
#pragma unroll
    for (int n = 0; n < 4; ++n)
      bf[n] = __builtin_bit_cast(
          bf16_8, *(const s16x8*)&Bs[cur][(wn * 64 + n * 16 + l15) * 32 + g * 8]);
#pragma unroll
    for (int m = 0; m < 4; ++m)
#pragma unroll
      for (int n = 0; n < 4; ++n)
        acc[m][n] = __builtin_amdgcn_mfma_f32_16x16x32_bf16(af[m], bf[n],
                                                            acc[m][n], 0, 0, 0);
    __syncthreads();
    cur ^= 1;
  }

  const int orow = row0 + wm * 64;
  const int ocol = col0 + wn * 64;
#pragma unroll
  for (int m = 0; m < 4; ++m)
#pragma unroll
    for (int n = 0; n < 4; ++n) {
      const int f = ocol + n * 16 + l15;
      const float bv = bias[f];
#pragma unroll
      for (int j = 0; j < 4; ++j)
        outf[(size_t)(orow + m * 16 + g * 4 + j) * EDIM + f] =
            acc[m][n][j] + bv;
    }
}

// ---------------------------------------------------------------------------
// Attention split-K: blockIdx.z picks key-half [z*1024, z*1024+1024).
// K/V LDS double-buffered via gload_lds, panel layout [2][64][32] u16 per
// array (wave-linear dest); ONE barrier per tile. Un-normalized O (bf16) +
// rowsum (f32) written per split; combine kernel normalizes.
// QK/PV math identical to R5/R6-verified path; Pl swizzle unchanged.
// ---------------------------------------------------------------------------
__global__ __launch_bounds__(256) void attn_split(
    const u16* __restrict__ Qs, const u16* __restrict__ Ks,
    const u16* __restrict__ Vt, u16* __restrict__ op0, u16* __restrict__ op1,
    float* __restrict__ rsp) {
  __shared__ u16 KVs[2][8192];     // [buf]: K panels @0,2048; V panels @4096,6144
  __shared__ u16 Pl[4][2][1024];   // per-wave swizzled P
  const int tid = threadIdx.x;
  const int wid = tid >> 6, lane = tid & 63;
  const int g = lane >> 4, l15 = lane & 15;
  const int bh = blockIdx.y, z = blockIdx.z;
  const int kt0 = z * (NQ / 2);
  const int qrow = blockIdx.x * 128 + wid * 32;
  const int rxor = (l15 >> 1) & 7;
  const int r4 = tid >> 2, c8 = (tid & 3) * 8;

  auto STAGE = [&](int buf, int kt) {
#pragma unroll
    for (int p = 0; p < 2; ++p) {
      gload16(&Ks[((size_t)bh * NQ + kt + r4) * HDIM + p * 32 + c8],
              &KVs[buf][p * 2048 + wid * 512]);
      gload16(&Vt[((size_t)bh * HDIM + r4) * NQ + kt + p * 32 + c8],
              &KVs[buf][4096 + p * 2048 + wid * 512]);
    }
  };

  bf16_8 qf[2][2];
#pragma unroll
  for (int qb = 0; qb < 2; ++qb)
#pragma unroll
    for (int c = 0; c < 2; ++c)
      qf[qb][c] = __builtin_bit_cast(
          bf16_8, *(const s16x8*)&Qs[((size_t)bh * NQ + qrow + qb * 16 + l15) *
                                         HDIM + c * 32 + g * 8]);

  f32x4 oacc[2][4];
#pragma unroll
  for (int qb = 0; qb < 2; ++qb)
#pragma unroll
    for (int n = 0; n < 4; ++n) oacc[qb][n] = f32x4{0.f, 0.f, 0.f, 0.f};
  float rs[2][4] = {{0.f, 0.f, 0.f, 0.f}, {0.f, 0.f, 0.f, 0.f}};

  STAGE(0, kt0);
  __syncthreads();
  int cur = 0;
  for (int t = 0; t < 16; ++t) {
    if (t < 15) STAGE(cur ^ 1, kt0 + (t + 1) * 64);

    // S = QK^T: lane holds S[q=4g+j][key=16n+l15]; P -> swizzled Pl
#pragma unroll
    for (int n = 0; n < 4; ++n) {
      bf16_8 kf0 = __builtin_bit_cast(
          bf16_8, *(const s16x8*)&KVs[cur][(n * 16 + l15) * 32 + g * 8]);
      bf16_8 kf1 = __builtin_bit_cast(
          bf16_8, *(const s16x8*)&KVs[cur][2048 + (n * 16 + l15) * 32 + g * 8]);
      const int chunk = 2 * n + (l15 >> 3), wsub = l15 & 7;
#pragma unroll
      for (int qb = 0; qb < 2; ++qb) {
        f32x4 s = f32x4{0.f, 0.f, 0.f, 0.f};
        s = __builtin_amdgcn_mfma_f32_16x16x32_bf16(qf[qb][0], kf0, s, 0, 0, 0);
        s = __builtin_amdgcn_mfma_f32_16x16x32_bf16(qf[qb][1], kf1, s, 0, 0, 0);
#pragma unroll
        for (int j = 0; j < 4; ++j) {
          float p = __expf(s[j]);
          rs[qb][j] += p;
          const int q = g * 4 + j;
          Pl[wid][qb][q * 64 + ((chunk ^ ((q >> 1) & 7)) << 3) + wsub] = f2bf(p);
        }
      }
    }

    // O += P*V
#pragma unroll
    for (int n = 0; n < 4; ++n) {
      bf16_8 vf0 = __builtin_bit_cast(
          bf16_8, *(const s16x8*)&KVs[cur][4096 + (n * 16 + l15) * 32 + g * 8]);
      bf16_8 vf1 = __builtin_bit_cast(
          bf16_8, *(const s16x8*)&KVs[cur][6144 + (n * 16 + l15) * 32 + g * 8]);
#pragma unroll
      for (int qb = 0; qb < 2; ++qb) {
        bf16_8 pf0 = __builtin_bit_cast(
            bf16_8, *(const s16x8*)&Pl[wid][qb][l15 * 64 + ((g ^ rxor) << 3)]);
        bf16_8 pf1 = __builtin_bit_cast(
            bf16_8, *(const s16x8*)&Pl[wid][qb][l15 * 64 + (((g + 4) ^ rxor) << 3)]);
        oacc[qb][n] = __builtin_amdgcn_mfma_f32_16x16x32_bf16(pf0, vf0, oacc[qb][n], 0, 0, 0);
        oacc[qb][n] = __builtin_amdgcn_mfma_f32_16x16x32_bf16(pf1, vf1, oacc[qb][n], 0, 0, 0);
      }
    }
    __syncthreads();
    cur ^= 1;
  }

  u16* op = z ? op1 : op0;
  const int b = bh >> 4, h = bh & 15;
#pragma unroll
  for (int qb = 0; qb < 2; ++qb) {
#pragma unroll
    for (int j = 0; j < 4; ++j) {
      float ts = rs[qb][j];
      ts += __shfl_xor(ts, 1);
      ts += __shfl_xor(ts, 2);
      ts += __shfl_xor(ts, 4);
      ts += __shfl_xor(ts, 8);
      if (l15 == 0)
        rsp[(size_t)(z * 32 + bh) * NQ + qrow + qb * 16 + g * 4 + j] = ts;
    }
#pragma unroll
    for (int n = 0; n < 4; ++n)
#pragma unroll
      for (int j = 0; j < 4; ++j) {
        const int q = qrow + qb * 16 + g * 4 + j;
        op[((size_t)q * BSZ + b) * EDIM + h * 64 + n * 16 + l15] =
            f2bf(oacc[qb][n][j]);
      }
  }
}

// ---------------------------------------------------------------------------
// Combine: AO[i] = (p0[i] + p1[i]) / (rs0 + rs1). In-place on p0 region.
// ---------------------------------------------------------------------------
__global__ __launch_bounds__(256) void attn_combine(
    const u16* __restrict__ p0, const u16* __restrict__ p1,
    const float* __restrict__ rsp, u16* __restrict__ AO) {
  const size_t i8 = (size_t)blockIdx.x * 256 + threadIdx.x;
  const size_t i = i8 * 8;  // grid sized so one element-octet per thread
  const int e = (int)(i & 1023);
  const int b = (int)((i >> 10) & 1);
  const int q = (int)(i >> 11);
  const int bh = b * NH + (e >> 6);
  const float inv = 1.0f / (rsp[(size_t)bh * NQ + q] +
                            rsp[(size_t)(32 + bh) * NQ + q]);
  s16x8 a = *(const s16x8*)&p0[i];
  s16x8 c = *(const s16x8*)&p1[i];
  s16x8 o;
#pragma unroll
  for (int j = 0; j < 8; ++j)
    o[j] = (short)f2bf((bf2f((u16)a[j]) + bf2f((u16)c[j])) * inv);
  *(s16x8*)&AO[i] = o;
}

// ---------------------------------------------------------------------------
extern "C" void kernel_launch(void* const* d_in, const int* in_sizes, int n_in,
                              void* d_out, int out_size, void* d_ws,
                              size_t ws_size, hipStream_t stream) {
  const float* seq = (const float*)d_in[0];
  const float* w_qkv = (const float*)d_in[1];
  const float* b_qkv = (const float*)d_in[2];
  const float* w_out = (const float*)d_in[3];
  const float* b_out = (const float*)d_in[4];
  float* out = (float*)d_out;

  const size_t per = (size_t)BSZ * NH * NQ * HDIM;  // 4,194,304
  u16* Qs = (u16*)d_ws;
  u16* Ks = Qs + per;
  u16* Vt = Ks + per;
  u16* AO = Vt + per;                       // final attn out; also O-partial z=0
  u16* seqb = AO + (size_t)MROWS * EDIM;    // dead after gemm_qkv -> O-partial z=1
  u16* wqkvb = seqb + (size_t)MROWS * EDIM; // dead after gemm_qkv -> rsp
  u16* woutb = wqkvb + (size_t)F3 * EDIM;
  float* rsp = (float*)wqkvb;

  cvt_f32_bf16<<<1024, 256, 0, stream>>>(seq, seqb, MROWS * EDIM);
  cvt_f32_bf16<<<1024, 256, 0, stream>>>(w_qkv, wqkvb, F3 * EDIM);
  cvt_f32_bf16<<<512, 256, 0, stream>>>(w_out, woutb, EDIM * EDIM);

  gemm_qkv<<<dim3(F3 / 192, MROWS / 256), 512, 0, stream>>>(
      seqb, wqkvb, b_qkv, Qs, Ks, Vt);
  attn_split<<<dim3(NQ / 128, BSZ * NH, 2), 256, 0, stream>>>(
      Qs, Ks, Vt, AO, seqb, rsp);
  attn_combine<<<(MROWS * EDIM) / (256 * 8), 256, 0, stream>>>(
      AO, seqb, rsp, AO);
  gemm_out<<<dim3(EDIM / 128, MROWS / 128), 256, 0, stream>>>(
      AO, woutb, b_out, out);
}

// Round 8
// 223.695 us; speedup vs baseline: 2.1750x; 1.0535x over previous
//
#include <hip/hip_runtime.h>

typedef unsigned short u16;
typedef unsigned int u32;
typedef __bf16 bf16_8 __attribute__((ext_vector_type(8)));
typedef short s16x8 __attribute__((ext_vector_type(8)));
typedef short s16x4 __attribute__((ext_vector_type(4)));
typedef float f32x4 __attribute__((ext_vector_type(4)));

#define NQ 2048
#define BSZ 2
#define EDIM 1024
#define NH 16
#define HDIM 64
#define MROWS (NQ * BSZ)   // 4096
#define F3 (3 * EDIM)      // 3072

// Q pre-scale: 1/sqrt(64) * log2(e)  -> softmax via native exp2
#define QSCALE 0.1803368801f

#if defined(__HIP_DEVICE_COMPILE__) && __has_builtin(__builtin_amdgcn_exp2f)
#define EXP2F(x) __builtin_amdgcn_exp2f(x)
#else
#define EXP2F(x) exp2f(x)
#endif

__device__ __forceinline__ float bf2f(u16 u) {
  u32 x = ((u32)u) << 16;
  return __builtin_bit_cast(float, x);
}
__device__ __forceinline__ u16 f2bf(float f) {
  u32 x = __builtin_bit_cast(u32, f);
  x += 0x7fff + ((x >> 16) & 1);  // RNE
  return (u16)(x >> 16);
}
__device__ __forceinline__ void gload16(const u16* g, u16* l) {
  __builtin_amdgcn_global_load_lds(
      (const __attribute__((address_space(1))) void*)g,
      (__attribute__((address_space(3))) void*)l, 16, 0, 0);
}

// ---------------------------------------------------------------------------
__global__ __launch_bounds__(256) void cvt_f32_bf16(
    const float* __restrict__ in, u16* __restrict__ out, int n) {
  int i = (blockIdx.x * 256 + threadIdx.x) * 4;
  const int stride = gridDim.x * 256 * 4;
  for (; i < n; i += stride) {
    f32x4 v = *(const f32x4*)&in[i];
    s16x4 o;
    o[0] = (short)f2bf(v[0]);
    o[1] = (short)f2bf(v[1]);
    o[2] = (short)f2bf(v[2]);
    o[3] = (short)f2bf(v[3]);
    *(s16x4*)&out[i] = o;
  }
}

// ---------------------------------------------------------------------------
// GEMM C = A*B^T + bias. 128x128, 4 waves, BK=32, dbuf gload_lds staging,
// ONE barrier/iter (R7-verified). Grid 768 (MODE0) = 3 blocks/CU exact.
// MODE 0: scatter into Qs (x QSCALE), Ks, Vt.  MODE 1: fp32 out.
// ---------------------------------------------------------------------------
template <int MODE>
__global__ __launch_bounds__(256) void gemm_bt(
    const u16* __restrict__ A, const u16* __restrict__ B,
    const float* __restrict__ bias,
    u16* __restrict__ out0, u16* __restrict__ out1, u16* __restrict__ out2,
    float* __restrict__ outf) {
  constexpr int K = EDIM;
  __shared__ u16 As[2][128 * 32];
  __shared__ u16 Bs[2][128 * 32];
  const int tid = threadIdx.x;
  const int wid = tid >> 6, lane = tid & 63;
  const int wm = wid >> 1, wn = wid & 1;
  const int row0 = blockIdx.y * 128, col0 = blockIdx.x * 128;
  const int g = lane >> 4, l15 = lane & 15;
  const int lr = tid >> 2, lc8 = (tid & 3) * 8;  // 64 rows x 4 granules

  auto STAGE = [&](int buf, int kb) {
#pragma unroll
    for (int s = 0; s < 2; ++s) {
      gload16(&A[(size_t)(row0 + s * 64 + lr) * K + kb + lc8],
              &As[buf][s * 2048 + wid * 512]);
      gload16(&B[(size_t)(col0 + s * 64 + lr) * K + kb + lc8],
              &Bs[buf][s * 2048 + wid * 512]);
    }
  };

  f32x4 acc[4][4];
#pragma unroll
  for (int m = 0; m < 4; ++m)
#pragma unroll
    for (int n = 0; n < 4; ++n) acc[m][n] = f32x4{0.f, 0.f, 0.f, 0.f};

  STAGE(0, 0);
  __syncthreads();
  int cur = 0;
  for (int t = 0; t < 32; ++t) {
    if (t < 31) STAGE(cur ^ 1, (t + 1) * 32);
    bf16_8 af[4], bf[4];
#pragma unroll
    for (int m = 0; m < 4; ++m)
      af[m] = __builtin_bit_cast(
          bf16_8, *(const s16x8*)&As[cur][(wm * 64 + m * 16 + l15) * 32 + g * 8]);
#pragma unroll
    for (int n = 0; n < 4; ++n)
      bf[n] = __builtin_bit_cast(
          bf16_8, *(const s16x8*)&Bs[cur][(wn * 64 + n * 16 + l15) * 32 + g * 8]);
#pragma unroll
    for (int m = 0; m < 4; ++m)
#pragma unroll
      for (int n = 0; n < 4; ++n)
        acc[m][n] = __builtin_amdgcn_mfma_f32_16x16x32_bf16(af[m], bf[n],
                                                            acc[m][n], 0, 0, 0);
    __syncthreads();
    cur ^= 1;
  }

  const int orow = row0 + wm * 64;
  const int ocol = col0 + wn * 64;
#pragma unroll
  for (int m = 0; m < 4; ++m) {
#pragma unroll
    for (int n = 0; n < 4; ++n) {
      const int f = ocol + n * 16 + l15;
      const float bv = bias[f];
#pragma unroll
      for (int j = 0; j < 4; ++j) {
        const int r = orow + m * 16 + g * 4 + j;
        const float v = acc[m][n][j] + bv;
        if (MODE == 0) {
          const int part = f >> 10, e = f & 1023;
          const int h = e >> 6, d = e & 63;
          const int nq = r >> 1, b = r & 1;
          const int bh = b * NH + h;
          if (part == 0)
            out0[((size_t)bh * NQ + nq) * HDIM + d] = f2bf(v * QSCALE);
          else if (part == 1)
            out1[((size_t)bh * NQ + nq) * HDIM + d] = f2bf(v);
          else
            out2[((size_t)bh * HDIM + d) * NQ + nq] = f2bf(v);
        } else {
          outf[(size_t)r * EDIM + f] = v;
        }
      }
    }
  }
}

// ---------------------------------------------------------------------------
// Attention split-K (z = key-half). K/V dbuf via gload_lds (32KB) + ONE
// shared P buffer (8KB, qb processed sequentially) -> 40KB LDS = 4 blocks/CU,
// grid 1024 = 4/CU exact. Softmax in exp2 domain (Q pre-scaled by ln2 fold).
// Un-normalized O (bf16) + rowsum (f32) per split; combine normalizes.
// ---------------------------------------------------------------------------
__global__ __launch_bounds__(256) void attn_split(
    const u16* __restrict__ Qs, const u16* __restrict__ Ks,
    const u16* __restrict__ Vt, u16* __restrict__ op0, u16* __restrict__ op1,
    float* __restrict__ rsp) {
  __shared__ u16 KVs[2][8192];   // K panels @0,2048; V panels @4096,6144
  __shared__ u16 Pl[4][1024];    // per-wave swizzled P (one qb at a time)
  const int tid = threadIdx.x;
  const int wid = tid >> 6, lane = tid & 63;
  const int g = lane >> 4, l15 = lane & 15;
  const int bh = blockIdx.y, z = blockIdx.z;
  const int kt0 = z * (NQ / 2);
  const int qrow = blockIdx.x * 128 + wid * 32;
  const int rxor = (l15 >> 1) & 7;
  const int r4 = tid >> 2, c8 = (tid & 3) * 8;

  auto STAGE = [&](int buf, int kt) {
#pragma unroll
    for (int p = 0; p < 2; ++p) {
      gload16(&Ks[((size_t)bh * NQ + kt + r4) * HDIM + p * 32 + c8],
              &KVs[buf][p * 2048 + wid * 512]);
      gload16(&Vt[((size_t)bh * HDIM + r4) * NQ + kt + p * 32 + c8],
              &KVs[buf][4096 + p * 2048 + wid * 512]);
    }
  };

  bf16_8 qf[2][2];
#pragma unroll
  for (int qb = 0; qb < 2; ++qb)
#pragma unroll
    for (int c = 0; c < 2; ++c)
      qf[qb][c] = __builtin_bit_cast(
          bf16_8, *(const s16x8*)&Qs[((size_t)bh * NQ + qrow + qb * 16 + l15) *
                                         HDIM + c * 32 + g * 8]);

  f32x4 oacc[2][4];
#pragma unroll
  for (int qb = 0; qb < 2; ++qb)
#pragma unroll
    for (int n = 0; n < 4; ++n) oacc[qb][n] = f32x4{0.f, 0.f, 0.f, 0.f};
  float rs[2][4] = {{0.f, 0.f, 0.f, 0.f}, {0.f, 0.f, 0.f, 0.f}};

  STAGE(0, kt0);
  __syncthreads();
  int cur = 0;
  for (int t = 0; t < 16; ++t) {
    if (t < 15) STAGE(cur ^ 1, kt0 + (t + 1) * 64);

#pragma unroll
    for (int qb = 0; qb < 2; ++qb) {
      // S = QK^T (log2 domain): lane holds S[q=4g+j][key=16n+l15]
#pragma unroll
      for (int n = 0; n < 4; ++n) {
        bf16_8 kf0 = __builtin_bit_cast(
            bf16_8, *(const s16x8*)&KVs[cur][(n * 16 + l15) * 32 + g * 8]);
        bf16_8 kf1 = __builtin_bit_cast(
            bf16_8, *(const s16x8*)&KVs[cur][2048 + (n * 16 + l15) * 32 + g * 8]);
        const int chunk = 2 * n + (l15 >> 3), wsub = l15 & 7;
        f32x4 s = f32x4{0.f, 0.f, 0.f, 0.f};
        s = __builtin_amdgcn_mfma_f32_16x16x32_bf16(qf[qb][0], kf0, s, 0, 0, 0);
        s = __builtin_amdgcn_mfma_f32_16x16x32_bf16(qf[qb][1], kf1, s, 0, 0, 0);
#pragma unroll
        for (int j = 0; j < 4; ++j) {
          float p = EXP2F(s[j]);
          rs[qb][j] += p;
          const int q = g * 4 + j;
          Pl[wid][q * 64 + ((chunk ^ ((q >> 1) & 7)) << 3) + wsub] = f2bf(p);
        }
      }
      // O += P*V (same-wave Pl RAW/WAR handled by lgkmcnt ordering)
#pragma unroll
      for (int n = 0; n < 4; ++n) {
        bf16_8 vf0 = __builtin_bit_cast(
            bf16_8, *(const s16x8*)&KVs[cur][4096 + (n * 16 + l15) * 32 + g * 8]);
        bf16_8 vf1 = __builtin_bit_cast(
            bf16_8, *(const s16x8*)&KVs[cur][6144 + (n * 16 + l15) * 32 + g * 8]);
        bf16_8 pf0 = __builtin_bit_cast(
            bf16_8, *(const s16x8*)&Pl[wid][l15 * 64 + ((g ^ rxor) << 3)]);
        bf16_8 pf1 = __builtin_bit_cast(
            bf16_8, *(const s16x8*)&Pl[wid][l15 * 64 + (((g + 4) ^ rxor) << 3)]);
        oacc[qb][n] = __builtin_amdgcn_mfma_f32_16x16x32_bf16(pf0, vf0, oacc[qb][n], 0, 0, 0);
        oacc[qb][n] = __builtin_amdgcn_mfma_f32_16x16x32_bf16(pf1, vf1, oacc[qb][n], 0, 0, 0);
      }
    }
    __syncthreads();
    cur ^= 1;
  }

  u16* op = z ? op1 : op0;
  const int b = bh >> 4, h = bh & 15;
#pragma unroll
  for (int qb = 0; qb < 2; ++qb) {
#pragma unroll
    for (int j = 0; j < 4; ++j) {
      float ts = rs[qb][j];
      ts += __shfl_xor(ts, 1);
      ts += __shfl_xor(ts, 2);
      ts += __shfl_xor(ts, 4);
      ts += __shfl_xor(ts, 8);
      if (l15 == 0)
        rsp[(size_t)(z * 32 + bh) * NQ + qrow + qb * 16 + g * 4 + j] = ts;
    }
#pragma unroll
    for (int n = 0; n < 4; ++n)
#pragma unroll
      for (int j = 0; j < 4; ++j) {
        const int q = qrow + qb * 16 + g * 4 + j;
        op[((size_t)q * BSZ + b) * EDIM + h * 64 + n * 16 + l15] =
            f2bf(oacc[qb][n][j]);
      }
  }
}

// ---------------------------------------------------------------------------
__global__ __launch_bounds__(256) void attn_combine(
    const u16* __restrict__ p0, const u16* __restrict__ p1,
    const float* __restrict__ rsp, u16* __restrict__ AO) {
  const size_t i8 = (size_t)blockIdx.x * 256 + threadIdx.x;
  const size_t i = i8 * 8;
  const int e = (int)(i & 1023);
  const int b = (int)((i >> 10) & 1);
  const int q = (int)(i >> 11);
  const int bh = b * NH + (e >> 6);
  const float inv = 1.0f / (rsp[(size_t)bh * NQ + q] +
                            rsp[(size_t)(32 + bh) * NQ + q]);
  s16x8 a = *(const s16x8*)&p0[i];
  s16x8 c = *(const s16x8*)&p1[i];
  s16x8 o;
#pragma unroll
  for (int j = 0; j < 8; ++j)
    o[j] = (short)f2bf((bf2f((u16)a[j]) + bf2f((u16)c[j])) * inv);
  *(s16x8*)&AO[i] = o;
}

// ---------------------------------------------------------------------------
extern "C" void kernel_launch(void* const* d_in, const int* in_sizes, int n_in,
                              void* d_out, int out_size, void* d_ws,
                              size_t ws_size, hipStream_t stream) {
  const float* seq = (const float*)d_in[0];
  const float* w_qkv = (const float*)d_in[1];
  const float* b_qkv = (const float*)d_in[2];
  const float* w_out = (const float*)d_in[3];
  const float* b_out = (const float*)d_in[4];
  float* out = (float*)d_out;

  const size_t per = (size_t)BSZ * NH * NQ * HDIM;  // 4,194,304
  u16* Qs = (u16*)d_ws;
  u16* Ks = Qs + per;
  u16* Vt = Ks + per;
  u16* AO = Vt + per;                       // final attn out / O-partial z=0
  u16* seqb = AO + (size_t)MROWS * EDIM;    // dead after gemm_qkv -> O-partial z=1
  u16* wqkvb = seqb + (size_t)MROWS * EDIM; // dead after gemm_qkv -> rsp
  u16* woutb = wqkvb + (size_t)F3 * EDIM;
  float* rsp = (float*)wqkvb;

  cvt_f32_bf16<<<1024, 256, 0, stream>>>(seq, seqb, MROWS * EDIM);
  cvt_f32_bf16<<<1024, 256, 0, stream>>>(w_qkv, wqkvb, F3 * EDIM);
  cvt_f32_bf16<<<512, 256, 0, stream>>>(w_out, woutb, EDIM * EDIM);

  gemm_bt<0><<<dim3(F3 / 128, MROWS / 128), 256, 0, stream>>>(
      seqb, wqkvb, b_qkv, Qs, Ks, Vt, nullptr);
  attn_split<<<dim3(NQ / 128, BSZ * NH, 2), 256, 0, stream>>>(
      Qs, Ks, Vt, AO, seqb, rsp);
  attn_combine<<<(MROWS * EDIM) / (256 * 8), 256, 0, stream>>>(
      AO, seqb, rsp, AO);
  gemm_bt<1><<<dim3(EDIM / 128, MROWS / 128), 256, 0, stream>>>(
      AO, woutb, b_out, nullptr, nullptr, nullptr, out);
}